// Round 1
// baseline (188.429 us; speedup 1.0000x reference)
//
#include <hip/hip_runtime.h>

// VQ nearest-codebook: MFMA bf16 hi/lo filter + exact fp32-emulated rescore.
// R9: (1) block-shared B-frags via double-buffered LDS + global_load_lds(16B)
//     prefetch (L2 traffic 1.07GB -> 268MB, latency hidden by compute);
//     (2) packed-uint top-2 epilogue (distance bits are value-monotone since
//     D+1.5 in [1,2); index in low 10 bits -> 4 VALU/result, numpy tie-break
//     for free); (3) A = -(2x) and MFMA C-init = se+1.5 so acc IS the
//     distance; A-frags loaded direct from global (no x-LDS, one barrier/chunk).
//
// ref semantics (verified R2/R3/R6/R8): d[n,k] = fl(fl(sx+se) - chain),
// sx/se = numpy pairwise-8 tree of squares, chain = sequential FMA over d of
// (2x)*e, argmin first-index tie-break. Ambiguous rows (gap <= ~3.05e-5) get
// the exact fp32-emulated rescore.

#define D 64
#define K 1024
#define HW 4096
#define NTOTAL 131072

// workspace layout (bytes)
#define BF_OFF   0          // B-frags: 32 chunks * 8 frags * 64 lanes * 16B = 256 KB
#define SE_OFF   262144     // 4 KB
#define CNT_OFF  266240
#define LIST_OFF 266244
#define LIST_CAP 65536
#define WS_NEED  (266244 + LIST_CAP * 4)

// packed-gap margin: 2^17 packed units = 2^-15 = 3.05e-5 value gap.
// covers: 2 ref fp32 roundings (2*7.63e-6 at |sx+se|<128) + bf16 3-term
// approx (<1e-5) + packing quantization (2^-22).
#define MARGIN_P 131072u

typedef __attribute__((ext_vector_type(8))) short bf16x8;   // 8 bf16 = 4 VGPR
typedef __attribute__((ext_vector_type(4))) float f32x4;

__device__ __forceinline__ unsigned short bf16_rne(float f) {
    unsigned u = __float_as_uint(f);
    u += 0x7fffu + ((u >> 16) & 1u);
    return (unsigned short)(u >> 16);
}
__device__ __forceinline__ float bf16_to_f(unsigned short h) {
    return __uint_as_float(((unsigned)h) << 16);
}

// numpy pairwise sum, n=64: 8 accumulators + ((r0+r1)+(r2+r3))+((r4+r5)+(r6+r7))
__device__ __forceinline__ float np_sumsq64(const float* v) {
    float r[8];
#pragma unroll
    for (int j = 0; j < 8; ++j) r[j] = __fmul_rn(v[j], v[j]);
#pragma unroll
    for (int i = 8; i < 64; i += 8)
#pragma unroll
        for (int j = 0; j < 8; ++j)
            r[j] = __fadd_rn(r[j], __fmul_rn(v[i + j], v[i + j]));
    float s01 = __fadd_rn(r[0], r[1]), s23 = __fadd_rn(r[2], r[3]);
    float s45 = __fadd_rn(r[4], r[5]), s67 = __fadd_rn(r[6], r[7]);
    return __fadd_rn(__fadd_rn(s01, s23), __fadd_rn(s45, s67));
}

// --- prep: codebook -> se + B-frags in lane order; also zeroes CNT ---
// frag f = tc*4+j; j:0=eh d0-31,1=eh d32-63,2=el d0-31,3=el d32-63
// lane l = q*16+c16 holds code (chunk*32+tc*16+c16), d = q*8+32*(j&1) .. +8
__global__ __launch_bounds__(256) void prep_cb(const float* __restrict__ cb,
                                               char* __restrict__ ws) {
    if (blockIdx.x == 0 && threadIdx.x == 0) *(int*)(ws + CNT_OFF) = 0;
    int k = blockIdx.x * 256 + threadIdx.x;          // grid 4*256 = 1024
    const float* e = cb + k * D;
    float v[D];
#pragma unroll
    for (int d = 0; d < D; ++d) v[d] = e[d];
    ((float*)(ws + SE_OFF))[k] = np_sumsq64(v);
    unsigned short hh[D], ll[D];
#pragma unroll
    for (int d = 0; d < D; ++d) {
        hh[d] = bf16_rne(v[d]);
        ll[d] = bf16_rne(v[d] - bf16_to_f(hh[d]));
    }
    const int c = k >> 5, tc = (k >> 4) & 1, c16 = k & 15;
    uint4* bf = (uint4*)(ws + BF_OFF);
#pragma unroll
    for (int qd = 0; qd < 8; ++qd) {                 // d0 = qd*8
        int q = qd & 3, jh = qd >> 2;                // d0 = q*8 + 32*jh
        int l = q * 16 + c16;
        uint4 a, b;
        const unsigned short* h = hh + qd * 8;
        const unsigned short* lo = ll + qd * 8;
        a.x = h[0] | (h[1] << 16);  a.y = h[2] | (h[3] << 16);
        a.z = h[4] | (h[5] << 16);  a.w = h[6] | (h[7] << 16);
        b.x = lo[0] | (lo[1] << 16); b.y = lo[2] | (lo[3] << 16);
        b.z = lo[4] | (lo[5] << 16); b.w = lo[6] | (lo[7] << 16);
        bf[(c * 8 + tc * 4 + jh) * 64 + l]       = a;   // hi -> j=jh
        bf[(c * 8 + tc * 4 + 2 + jh) * 64 + l]   = b;   // lo -> j=2+jh
    }
}

// --- main ---
__global__ __launch_bounds__(256, 4) void vq_main(const float* __restrict__ in,
                                                  const float* __restrict__ cb,
                                                  float* __restrict__ out,
                                                  char* __restrict__ ws) {
    __shared__ uint4 s_bf[2][8][64];   // 16 KB double-buffered B-frag chunk
    __shared__ int s_widx[128];

    const int t = threadIdx.x;
    const int nb = blockIdx.x * 128;          // grid 1024
    const int b = nb >> 12, hw0 = nb & (HW - 1);
    const int lane = t & 63, q = lane >> 4, c16 = lane & 15, w = t >> 6;

    // ---- A-frags direct from global, fragment layout. A = -(2x), hi/lo split.
    // A[m=c16][k=q*8+i], d = 32*jh + q*8 + i. Rows: w*32 + tv*16 + c16.
    bf16x8 af[2][4];
#pragma unroll
    for (int tv = 0; tv < 2; ++tv) {
        const float* xp = in + (size_t)b * (D * HW) + hw0 + w * 32 + tv * 16 + c16;
        unsigned short h[16], l[16];
#pragma unroll
        for (int jh = 0; jh < 2; ++jh)
#pragma unroll
            for (int i = 0; i < 8; ++i) {
                float x = xp[(size_t)(jh * 32 + q * 8 + i) * HW];
                float ny = __fmul_rn(x, -2.0f);              // exact
                unsigned short nh = bf16_rne(ny);
                h[jh * 8 + i] = nh;
                l[jh * 8 + i] = bf16_rne(__fsub_rn(ny, bf16_to_f(nh)));
            }
#pragma unroll
        for (int jh = 0; jh < 2; ++jh) {
            bf16x8 vh, vl;
#pragma unroll
            for (int i = 0; i < 8; ++i) { vh[i] = (short)h[jh * 8 + i]; vl[i] = (short)l[jh * 8 + i]; }
            af[tv][jh]     = vh;     // j=0,1: hi
            af[tv][2 + jh] = vl;     // j=2,3: lo
        }
    }

    const float* seg = (const float*)(ws + SE_OFF);
    const char* bfbase = ws + BF_OFF;

    unsigned p1[8], p2[8];
#pragma unroll
    for (int s = 0; s < 8; ++s) { p1[s] = 0xFFFFFFFFu; p2[s] = 0xFFFFFFFFu; }

    // stage chunk 0 into buf 0 (wave w stages frags 2w, 2w+1; lane-ordered 16B)
    {
        const char* g = bfbase + ((size_t)(0 * 8 + 2 * w) * 64 + lane) * 16;
        __builtin_amdgcn_global_load_lds((const __attribute__((address_space(1))) void*)g,
            (__attribute__((address_space(3))) void*)&s_bf[0][2 * w][0], 16, 0, 0);
        __builtin_amdgcn_global_load_lds((const __attribute__((address_space(1))) void*)(g + 1024),
            (__attribute__((address_space(3))) void*)&s_bf[0][2 * w + 1][0], 16, 0, 0);
    }
    __syncthreads();

    for (int c = 0; c < 32; ++c) {
        const int cur = c & 1;
        if (c + 1 < 32) {   // prefetch next chunk into other buffer (async)
            const char* g = bfbase + ((size_t)((c + 1) * 8 + 2 * w) * 64 + lane) * 16;
            __builtin_amdgcn_global_load_lds((const __attribute__((address_space(1))) void*)g,
                (__attribute__((address_space(3))) void*)&s_bf[cur ^ 1][2 * w][0], 16, 0, 0);
            __builtin_amdgcn_global_load_lds((const __attribute__((address_space(1))) void*)(g + 1024),
                (__attribute__((address_space(3))) void*)&s_bf[cur ^ 1][2 * w + 1][0], 16, 0, 0);
        }

        float sec0 = __fadd_rn(seg[c * 32 + c16], 1.5f);
        float sec1 = __fadd_rn(seg[c * 32 + 16 + c16], 1.5f);

        bf16x8 bfr[2][4];
#pragma unroll
        for (int tc = 0; tc < 2; ++tc)
#pragma unroll
            for (int j = 0; j < 4; ++j)
                bfr[tc][j] = *(const bf16x8*)&s_bf[cur][tc * 4 + j][lane];

        f32x4 acc[2][2];
#pragma unroll
        for (int tv = 0; tv < 2; ++tv) {
            acc[tv][0] = (f32x4){sec0, sec0, sec0, sec0};
            acc[tv][1] = (f32x4){sec1, sec1, sec1, sec1};
        }

        // K=192: (-yh)*eh (2) + (-yl)*eh (2) + (-yh)*el (2) accumulated on se'
        const int sa[6] = {0, 1, 2, 3, 0, 1};
        const int sb[6] = {0, 1, 0, 1, 2, 3};
#pragma unroll
        for (int s = 0; s < 6; ++s)
#pragma unroll
            for (int tv = 0; tv < 2; ++tv)
#pragma unroll
                for (int tc = 0; tc < 2; ++tc)
                    acc[tv][tc] = __builtin_amdgcn_mfma_f32_16x16x32_bf16(
                        af[tv][sa[s]], bfr[tc][sb[s]], acc[tv][tc], 0, 0, 0);

        // epilogue: acc = se' - dot in [1.33,1.67] -> bits monotone.
        // p = ((bits>>1)<<10) | code ; top-2 via min/max/min. slot s=tv*4+r.
#pragma unroll
        for (int tv = 0; tv < 2; ++tv)
#pragma unroll
            for (int tc = 0; tc < 2; ++tc) {
                unsigned code = (unsigned)(c * 32 + tc * 16 + c16);
#pragma unroll
                for (int r = 0; r < 4; ++r) {
                    unsigned u = __float_as_uint(acc[tv][tc][r]);
                    unsigned p = ((u >> 1) << 10) | code;
                    int s = tv * 4 + r;
                    unsigned mx = p > p1[s] ? p : p1[s];
                    p2[s] = mx < p2[s] ? mx : p2[s];
                    p1[s] = p < p1[s] ? p : p1[s];
                }
            }
        __syncthreads();   // all waves done with buf cur; prefetch drained
    }

    // ---- cross-lane top-2 merge over the 16 col-lanes (bits 0-3 of lane)
#pragma unroll
    for (int m = 1; m < 16; m <<= 1)
#pragma unroll
        for (int s = 0; s < 8; ++s) {
            unsigned o1 = (unsigned)__shfl_xor((int)p1[s], m, 64);
            unsigned o2 = (unsigned)__shfl_xor((int)p2[s], m, 64);
            unsigned lo = p1[s] < o1 ? p1[s] : o1;
            unsigned hi = p1[s] < o1 ? o1 : p1[s];
            unsigned n2 = p2[s] < o2 ? p2[s] : o2;
            p2[s] = hi < n2 ? hi : n2;
            p1[s] = lo;
        }

    if (c16 == 0) {
#pragma unroll
        for (int s = 0; s < 8; ++s) {
            int tv = s >> 2, r = s & 3;
            int row = w * 32 + tv * 16 + q * 4 + r;    // block-local
            s_widx[row] = (int)(p1[s] & 1023u);
            if (p2[s] - p1[s] <= MARGIN_P) {
                int pos = atomicAdd((int*)(ws + CNT_OFF), 1);
                if (pos < LIST_CAP) ((int*)(ws + LIST_OFF))[pos] = nb + row;
            }
        }
    }
    __syncthreads();

    // ---- gather-write (stores coalesced across rows)
    {
        int r = t & 127, half = t >> 7;
        int widx = s_widx[r];
        const float4* er = (const float4*)(cb + (size_t)widx * D + half * 32);
        float* op = out + (size_t)b * (D * HW) + hw0 + r + (size_t)(half * 32) * HW;
#pragma unroll
        for (int i = 0; i < 8; ++i) {
            float4 v = er[i];
            op[(size_t)(i * 4 + 0) * HW] = v.x;
            op[(size_t)(i * 4 + 1) * HW] = v.y;
            op[(size_t)(i * 4 + 2) * HW] = v.z;
            op[(size_t)(i * 4 + 3) * HW] = v.w;
        }
    }
}

// --- rescore: exact fp32-emulated chain over all codes for flagged vectors ---
__global__ __launch_bounds__(64) void vq_rescore(const float* __restrict__ in,
                                                 const float* __restrict__ cb,
                                                 float* __restrict__ out,
                                                 char* __restrict__ ws) {
    int count = *(const int*)(ws + CNT_OFF);
    if (count > LIST_CAP) count = LIST_CAP;
    const int* list = (const int*)(ws + LIST_OFF);
    const float* seg = (const float*)(ws + SE_OFF);
    int lane = threadIdx.x;
    for (int i = blockIdx.x; i < count; i += gridDim.x) {
        int n = list[i];
        int b = n >> 12, hw = n & (HW - 1);
        const float* xin = in + (size_t)b * (D * HW) + hw;
        float x[D];
#pragma unroll
        for (int d = 0; d < D; ++d) x[d] = xin[(size_t)d * HW];
        float y[D];
#pragma unroll
        for (int d = 0; d < D; ++d) y[d] = __fadd_rn(x[d], x[d]);
        float sx = np_sumsq64(x);
        float best = 3.4e38f; int bidx = 0;
        for (int c = 0; c < 16; ++c) {
            int k = c * 64 + lane;                      // ascending k per lane
            const float4* e4 = (const float4*)(cb + (size_t)k * D);
            float acc = 0.f;
#pragma unroll
            for (int p = 0; p < 16; ++p) {              // exact sequential chain
                float4 ev = e4[p];
                acc = __fmaf_rn(y[p * 4 + 0], ev.x, acc);
                acc = __fmaf_rn(y[p * 4 + 1], ev.y, acc);
                acc = __fmaf_rn(y[p * 4 + 2], ev.z, acc);
                acc = __fmaf_rn(y[p * 4 + 3], ev.w, acc);
            }
            float dist = __fsub_rn(__fadd_rn(sx, seg[k]), acc);
            if (dist < best) { best = dist; bidx = k; }
        }
#pragma unroll
        for (int m = 1; m < 64; m <<= 1) {              // (val, idx) lex-min
            float ob = __shfl_xor(best, m, 64);
            int oi = __shfl_xor(bidx, m, 64);
            if (ob < best || (ob == best && oi < bidx)) { best = ob; bidx = oi; }
        }
        out[(size_t)b * (D * HW) + (size_t)lane * HW + hw] = cb[(size_t)bidx * D + lane];
    }
}

extern "C" void kernel_launch(void* const* d_in, const int* in_sizes, int n_in,
                              void* d_out, int out_size, void* d_ws, size_t ws_size,
                              hipStream_t stream) {
    const float* in = (const float*)d_in[0];
    const float* cb = (const float*)d_in[1];
    float* out = (float*)d_out;
    char* ws = (char*)d_ws;

    if (ws_size < (size_t)WS_NEED) return;   // fail visibly, never OOB

    prep_cb<<<dim3(K / 256), dim3(256), 0, stream>>>(cb, ws);
    vq_main<<<dim3(NTOTAL / 128), dim3(256), 0, stream>>>(in, cb, out, ws);
    vq_rescore<<<dim3(4096), dim3(64), 0, stream>>>(in, cb, out, ws);
}

// Round 2
// 187.917 us; speedup vs baseline: 1.0027x; 1.0027x over previous
//
#include <hip/hip_runtime.h>

// VQ nearest-codebook: MFMA bf16 hi/lo filter + exact fp32-emulated rescore.
// R9: (1) block-shared B-frags via double-buffered LDS + global_load_lds(16B)
//     prefetch; (2) packed-uint top-2 epilogue (distance bits value-monotone,
//     index in low 10 bits, numpy tie-break free); (3) A = -(2x), MFMA C-init
//     = se+1.5 so acc IS the distance.
// R10 (this round, VALU-issue-bound per rocprof: VALUBusy 42% > MfmaUtil 28%):
//     (a) v_med3_u32 second-best update: p2' = med3(p, p1, p2) == 2nd-smallest
//         given p1<=p2 invariant -> epilogue 5->4 VALU/candidate;
//     (b) v_cvt_pk_bf16_f32 (HW RNE) for A-frag hi/lo split -> A-prep
//         ~500 -> ~150 insts/wave;
//     (c) software-pipelined seg[] loads (chunk c+1 issued during chunk c).
//
// ref semantics (verified R2/R3/R6/R8): d[n,k] = fl(fl(sx+se) - chain),
// sx/se = numpy pairwise-8 tree of squares, chain = sequential FMA over d of
// (2x)*e, argmin first-index tie-break. Ambiguous rows (gap <= ~3.05e-5) get
// the exact fp32-emulated rescore.

#define D 64
#define K 1024
#define HW 4096
#define NTOTAL 131072

// workspace layout (bytes)
#define BF_OFF   0          // B-frags: 32 chunks * 8 frags * 64 lanes * 16B = 256 KB
#define SE_OFF   262144     // 4 KB
#define CNT_OFF  266240
#define LIST_OFF 266244
#define LIST_CAP 65536
#define WS_NEED  (266244 + LIST_CAP * 4)

// packed-gap margin: 2^17 packed units = 2^-15 = 3.05e-5 value gap.
// covers: 2 ref fp32 roundings (2*7.63e-6 at |sx+se|<128) + bf16 3-term
// approx (<1e-5) + packing quantization (2^-22).
#define MARGIN_P 131072u

typedef __attribute__((ext_vector_type(8))) short bf16x8;   // 8 bf16 = 4 VGPR
typedef __attribute__((ext_vector_type(4))) float f32x4;
typedef __attribute__((ext_vector_type(4))) unsigned int u32x4;

__device__ __forceinline__ unsigned short bf16_rne(float f) {
    unsigned u = __float_as_uint(f);
    u += 0x7fffu + ((u >> 16) & 1u);
    return (unsigned short)(u >> 16);
}
__device__ __forceinline__ float bf16_to_f(unsigned short h) {
    return __uint_as_float(((unsigned)h) << 16);
}

// HW packed f32->bf16 RNE convert: low16 = bf16(a), high16 = bf16(b).
__device__ __forceinline__ unsigned cvt_pk_bf16(float a, float b) {
    unsigned r;
    asm("v_cvt_pk_bf16_f32 %0, %1, %2" : "=v"(r) : "v"(a), "v"(b));
    return r;
}

// numpy pairwise sum, n=64: 8 accumulators + ((r0+r1)+(r2+r3))+((r4+r5)+(r6+r7))
__device__ __forceinline__ float np_sumsq64(const float* v) {
    float r[8];
#pragma unroll
    for (int j = 0; j < 8; ++j) r[j] = __fmul_rn(v[j], v[j]);
#pragma unroll
    for (int i = 8; i < 64; i += 8)
#pragma unroll
        for (int j = 0; j < 8; ++j)
            r[j] = __fadd_rn(r[j], __fmul_rn(v[i + j], v[i + j]));
    float s01 = __fadd_rn(r[0], r[1]), s23 = __fadd_rn(r[2], r[3]);
    float s45 = __fadd_rn(r[4], r[5]), s67 = __fadd_rn(r[6], r[7]);
    return __fadd_rn(__fadd_rn(s01, s23), __fadd_rn(s45, s67));
}

// --- prep: codebook -> se + B-frags in lane order; also zeroes CNT ---
// frag f = tc*4+j; j:0=eh d0-31,1=eh d32-63,2=el d0-31,3=el d32-63
// lane l = q*16+c16 holds code (chunk*32+tc*16+c16), d = q*8+32*(j&1) .. +8
__global__ __launch_bounds__(256) void prep_cb(const float* __restrict__ cb,
                                               char* __restrict__ ws) {
    if (blockIdx.x == 0 && threadIdx.x == 0) *(int*)(ws + CNT_OFF) = 0;
    int k = blockIdx.x * 256 + threadIdx.x;          // grid 4*256 = 1024
    const float* e = cb + k * D;
    float v[D];
#pragma unroll
    for (int d = 0; d < D; ++d) v[d] = e[d];
    ((float*)(ws + SE_OFF))[k] = np_sumsq64(v);
    unsigned short hh[D], ll[D];
#pragma unroll
    for (int d = 0; d < D; ++d) {
        hh[d] = bf16_rne(v[d]);
        ll[d] = bf16_rne(v[d] - bf16_to_f(hh[d]));
    }
    const int c = k >> 5, tc = (k >> 4) & 1, c16 = k & 15;
    uint4* bf = (uint4*)(ws + BF_OFF);
#pragma unroll
    for (int qd = 0; qd < 8; ++qd) {                 // d0 = qd*8
        int q = qd & 3, jh = qd >> 2;                // d0 = q*8 + 32*jh
        int l = q * 16 + c16;
        uint4 a, b;
        const unsigned short* h = hh + qd * 8;
        const unsigned short* lo = ll + qd * 8;
        a.x = h[0] | (h[1] << 16);  a.y = h[2] | (h[3] << 16);
        a.z = h[4] | (h[5] << 16);  a.w = h[6] | (h[7] << 16);
        b.x = lo[0] | (lo[1] << 16); b.y = lo[2] | (lo[3] << 16);
        b.z = lo[4] | (lo[5] << 16); b.w = lo[6] | (lo[7] << 16);
        bf[(c * 8 + tc * 4 + jh) * 64 + l]       = a;   // hi -> j=jh
        bf[(c * 8 + tc * 4 + 2 + jh) * 64 + l]   = b;   // lo -> j=2+jh
    }
}

// --- main ---
__global__ __launch_bounds__(256, 4) void vq_main(const float* __restrict__ in,
                                                  const float* __restrict__ cb,
                                                  float* __restrict__ out,
                                                  char* __restrict__ ws) {
    __shared__ uint4 s_bf[2][8][64];   // 16 KB double-buffered B-frag chunk
    __shared__ int s_widx[128];

    const int t = threadIdx.x;
    const int nb = blockIdx.x * 128;          // grid 1024
    const int b = nb >> 12, hw0 = nb & (HW - 1);
    const int lane = t & 63, q = lane >> 4, c16 = lane & 15, w = t >> 6;

    // ---- A-frags direct from global, fragment layout. A = -(2x), hi/lo split
    // via HW v_cvt_pk_bf16_f32 (RNE, matches sw bf16_rne bits).
    // A[m=c16][k=q*8+i], d = 32*jh + q*8 + i. Rows: w*32 + tv*16 + c16.
    bf16x8 af[2][4];
#pragma unroll
    for (int tv = 0; tv < 2; ++tv) {
        const float* xp = in + (size_t)b * (D * HW) + hw0 + w * 32 + tv * 16 + c16;
#pragma unroll
        for (int jh = 0; jh < 2; ++jh) {
            float ny[8];
#pragma unroll
            for (int i = 0; i < 8; ++i)
                ny[i] = __fmul_rn(xp[(size_t)(jh * 32 + q * 8 + i) * HW], -2.0f); // exact
            u32x4 hv, lv;
#pragma unroll
            for (int p = 0; p < 4; ++p) {
                unsigned hp = cvt_pk_bf16(ny[2 * p], ny[2 * p + 1]);
                float h0 = __uint_as_float(hp << 16);
                float h1 = __uint_as_float(hp & 0xFFFF0000u);
                unsigned lp = cvt_pk_bf16(__fsub_rn(ny[2 * p], h0),
                                          __fsub_rn(ny[2 * p + 1], h1));
                hv[p] = hp; lv[p] = lp;
            }
            af[tv][jh]     = __builtin_bit_cast(bf16x8, hv);   // j=0,1: hi
            af[tv][2 + jh] = __builtin_bit_cast(bf16x8, lv);   // j=2,3: lo
        }
    }

    const float* seg = (const float*)(ws + SE_OFF);
    const char* bfbase = ws + BF_OFF;

    unsigned p1[8], p2[8];
#pragma unroll
    for (int s = 0; s < 8; ++s) { p1[s] = 0xFFFFFFFFu; p2[s] = 0xFFFFFFFFu; }

    // stage chunk 0 into buf 0 (wave w stages frags 2w, 2w+1; lane-ordered 16B)
    {
        const char* g = bfbase + ((size_t)(0 * 8 + 2 * w) * 64 + lane) * 16;
        __builtin_amdgcn_global_load_lds((const __attribute__((address_space(1))) void*)g,
            (__attribute__((address_space(3))) void*)&s_bf[0][2 * w][0], 16, 0, 0);
        __builtin_amdgcn_global_load_lds((const __attribute__((address_space(1))) void*)(g + 1024),
            (__attribute__((address_space(3))) void*)&s_bf[0][2 * w + 1][0], 16, 0, 0);
    }
    // software-pipelined se loads for chunk 0
    float se0 = seg[c16], se1 = seg[16 + c16];
    __syncthreads();

    for (int c = 0; c < 32; ++c) {
        const int cur = c & 1;
        if (c + 1 < 32) {   // prefetch next chunk into other buffer (async)
            const char* g = bfbase + ((size_t)((c + 1) * 8 + 2 * w) * 64 + lane) * 16;
            __builtin_amdgcn_global_load_lds((const __attribute__((address_space(1))) void*)g,
                (__attribute__((address_space(3))) void*)&s_bf[cur ^ 1][2 * w][0], 16, 0, 0);
            __builtin_amdgcn_global_load_lds((const __attribute__((address_space(1))) void*)(g + 1024),
                (__attribute__((address_space(3))) void*)&s_bf[cur ^ 1][2 * w + 1][0], 16, 0, 0);
        }
        // issue next chunk's se loads early (hide L2 latency under this chunk)
        float nse0 = 0.f, nse1 = 0.f;
        if (c + 1 < 32) {
            nse0 = seg[(c + 1) * 32 + c16];
            nse1 = seg[(c + 1) * 32 + 16 + c16];
        }

        float sec0 = __fadd_rn(se0, 1.5f);
        float sec1 = __fadd_rn(se1, 1.5f);

        bf16x8 bfr[2][4];
#pragma unroll
        for (int tc = 0; tc < 2; ++tc)
#pragma unroll
            for (int j = 0; j < 4; ++j)
                bfr[tc][j] = *(const bf16x8*)&s_bf[cur][tc * 4 + j][lane];

        f32x4 acc[2][2];
#pragma unroll
        for (int tv = 0; tv < 2; ++tv) {
            acc[tv][0] = (f32x4){sec0, sec0, sec0, sec0};
            acc[tv][1] = (f32x4){sec1, sec1, sec1, sec1};
        }

        // K=192: (-yh)*eh (2) + (-yl)*eh (2) + (-yh)*el (2) accumulated on se'
        const int sa[6] = {0, 1, 2, 3, 0, 1};
        const int sb[6] = {0, 1, 0, 1, 2, 3};
#pragma unroll
        for (int s = 0; s < 6; ++s)
#pragma unroll
            for (int tv = 0; tv < 2; ++tv)
#pragma unroll
                for (int tc = 0; tc < 2; ++tc)
                    acc[tv][tc] = __builtin_amdgcn_mfma_f32_16x16x32_bf16(
                        af[tv][sa[s]], bfr[tc][sb[s]], acc[tv][tc], 0, 0, 0);

        // epilogue: acc = se' - dot in [1.33,1.67] -> bits monotone.
        // p = ((bits>>1)<<10) | code. top-2: p2' = med3(p, p1, p2) is the
        // 2nd-smallest given the p1<=p2 invariant (init equal, preserved);
        // p1' = min(p, p1). 4 VALU/candidate.
#pragma unroll
        for (int tv = 0; tv < 2; ++tv)
#pragma unroll
            for (int tc = 0; tc < 2; ++tc) {
                unsigned code = (unsigned)(c * 32 + tc * 16 + c16);
#pragma unroll
                for (int r = 0; r < 4; ++r) {
                    unsigned u = __float_as_uint(acc[tv][tc][r]);
                    unsigned p = ((u >> 1) << 10) | code;
                    int s = tv * 4 + r;
                    unsigned m;
                    asm("v_med3_u32 %0, %1, %2, %3"
                        : "=v"(m) : "v"(p), "v"(p1[s]), "v"(p2[s]));
                    p2[s] = m;
                    p1[s] = p < p1[s] ? p : p1[s];
                }
            }
        se0 = nse0; se1 = nse1;
        __syncthreads();   // all waves done with buf cur; prefetch drained
    }

    // ---- cross-lane top-2 merge over the 16 col-lanes (bits 0-3 of lane)
#pragma unroll
    for (int m = 1; m < 16; m <<= 1)
#pragma unroll
        for (int s = 0; s < 8; ++s) {
            unsigned o1 = (unsigned)__shfl_xor((int)p1[s], m, 64);
            unsigned o2 = (unsigned)__shfl_xor((int)p2[s], m, 64);
            unsigned lo = p1[s] < o1 ? p1[s] : o1;
            unsigned hi = p1[s] < o1 ? o1 : p1[s];
            unsigned n2 = p2[s] < o2 ? p2[s] : o2;
            p2[s] = hi < n2 ? hi : n2;
            p1[s] = lo;
        }

    if (c16 == 0) {
#pragma unroll
        for (int s = 0; s < 8; ++s) {
            int tv = s >> 2, r = s & 3;
            int row = w * 32 + tv * 16 + q * 4 + r;    // block-local
            s_widx[row] = (int)(p1[s] & 1023u);
            if (p2[s] - p1[s] <= MARGIN_P) {
                int pos = atomicAdd((int*)(ws + CNT_OFF), 1);
                if (pos < LIST_CAP) ((int*)(ws + LIST_OFF))[pos] = nb + row;
            }
        }
    }
    __syncthreads();

    // ---- gather-write (stores coalesced across rows)
    {
        int r = t & 127, half = t >> 7;
        int widx = s_widx[r];
        const float4* er = (const float4*)(cb + (size_t)widx * D + half * 32);
        float* op = out + (size_t)b * (D * HW) + hw0 + r + (size_t)(half * 32) * HW;
#pragma unroll
        for (int i = 0; i < 8; ++i) {
            float4 v = er[i];
            op[(size_t)(i * 4 + 0) * HW] = v.x;
            op[(size_t)(i * 4 + 1) * HW] = v.y;
            op[(size_t)(i * 4 + 2) * HW] = v.z;
            op[(size_t)(i * 4 + 3) * HW] = v.w;
        }
    }
}

// --- rescore: exact fp32-emulated chain over all codes for flagged vectors ---
__global__ __launch_bounds__(64) void vq_rescore(const float* __restrict__ in,
                                                 const float* __restrict__ cb,
                                                 float* __restrict__ out,
                                                 char* __restrict__ ws) {
    int count = *(const int*)(ws + CNT_OFF);
    if (count > LIST_CAP) count = LIST_CAP;
    const int* list = (const int*)(ws + LIST_OFF);
    const float* seg = (const float*)(ws + SE_OFF);
    int lane = threadIdx.x;
    for (int i = blockIdx.x; i < count; i += gridDim.x) {
        int n = list[i];
        int b = n >> 12, hw = n & (HW - 1);
        const float* xin = in + (size_t)b * (D * HW) + hw;
        float x[D];
#pragma unroll
        for (int d = 0; d < D; ++d) x[d] = xin[(size_t)d * HW];
        float y[D];
#pragma unroll
        for (int d = 0; d < D; ++d) y[d] = __fadd_rn(x[d], x[d]);
        float sx = np_sumsq64(x);
        float best = 3.4e38f; int bidx = 0;
        for (int c = 0; c < 16; ++c) {
            int k = c * 64 + lane;                      // ascending k per lane
            const float4* e4 = (const float4*)(cb + (size_t)k * D);
            float acc = 0.f;
#pragma unroll
            for (int p = 0; p < 16; ++p) {              // exact sequential chain
                float4 ev = e4[p];
                acc = __fmaf_rn(y[p * 4 + 0], ev.x, acc);
                acc = __fmaf_rn(y[p * 4 + 1], ev.y, acc);
                acc = __fmaf_rn(y[p * 4 + 2], ev.z, acc);
                acc = __fmaf_rn(y[p * 4 + 3], ev.w, acc);
            }
            float dist = __fsub_rn(__fadd_rn(sx, seg[k]), acc);
            if (dist < best) { best = dist; bidx = k; }
        }
#pragma unroll
        for (int m = 1; m < 64; m <<= 1) {              // (val, idx) lex-min
            float ob = __shfl_xor(best, m, 64);
            int oi = __shfl_xor(bidx, m, 64);
            if (ob < best || (ob == best && oi < bidx)) { best = ob; bidx = oi; }
        }
        out[(size_t)b * (D * HW) + (size_t)lane * HW + hw] = cb[(size_t)bidx * D + lane];
    }
}

extern "C" void kernel_launch(void* const* d_in, const int* in_sizes, int n_in,
                              void* d_out, int out_size, void* d_ws, size_t ws_size,
                              hipStream_t stream) {
    const float* in = (const float*)d_in[0];
    const float* cb = (const float*)d_in[1];
    float* out = (float*)d_out;
    char* ws = (char*)d_ws;

    if (ws_size < (size_t)WS_NEED) return;   // fail visibly, never OOB

    prep_cb<<<dim3(K / 256), dim3(256), 0, stream>>>(cb, ws);
    vq_main<<<dim3(NTOTAL / 128), dim3(256), 0, stream>>>(in, cb, out, ws);
    vq_rescore<<<dim3(4096), dim3(64), 0, stream>>>(in, cb, out, ws);
}